// Round 3
// baseline (719.500 us; speedup 1.0000x reference)
//
#include <hip/hip_runtime.h>
#include <math.h>

#define IN_D 128
#define HID 64

typedef unsigned short ushort_t;
typedef unsigned int uint_t;

static __device__ __forceinline__ ushort_t f2bf(float f) {
    uint_t x = __float_as_uint(f);
    uint_t r = x + 0x7fffu + ((x >> 16) & 1u);   // RTN-even
    return (ushort_t)(r >> 16);
}
static __device__ __forceinline__ float bf2f(ushort_t u) {
    return __uint_as_float(((uint_t)u) << 16);
}

// ---------------- utility kernels ----------------

__global__ void zero2_kernel(int* a, int* b, int n) {
    int i = blockIdx.x * blockDim.x + threadIdx.x;
    if (i < n) { a[i] = 0; b[i] = 0; }
}

__global__ void hist_kernel(const int* __restrict__ dst, int E, int* __restrict__ cnt) {
    int e = blockIdx.x * blockDim.x + threadIdx.x;
    if (e < E) atomicAdd(&cnt[dst[e]], 1);
}

// inclusive scan within 1024-blocks; writes row_ptr[i+1], block totals; fused deg->nrm/invdt
__global__ void scan1_kernel(const int* __restrict__ cnt, int N,
                             int* __restrict__ row_ptr, int* __restrict__ blocksum,
                             float* __restrict__ nrm, float* __restrict__ invdt) {
    __shared__ int sm[1024];
    int i = blockIdx.x * 1024 + threadIdx.x;
    int v = (i < N) ? cnt[i] : 0;
    if (i < N) {
        float d = (float)v;
        nrm[i] = 1.0f / sqrtf(d);    // lam=1: dt = deg
        invdt[i] = 1.0f / d;
    }
    sm[threadIdx.x] = v;
    __syncthreads();
    for (int off = 1; off < 1024; off <<= 1) {
        int t = (threadIdx.x >= off) ? sm[threadIdx.x - off] : 0;
        __syncthreads();
        sm[threadIdx.x] += t;
        __syncthreads();
    }
    if (i < N) row_ptr[i + 1] = sm[threadIdx.x];
    if (threadIdx.x == 1023) blocksum[blockIdx.x] = sm[1023];
}

__global__ void scan2_kernel(int* __restrict__ blocksum, int nb) {
    __shared__ int sm[1024];
    int v = (threadIdx.x < nb) ? blocksum[threadIdx.x] : 0;
    sm[threadIdx.x] = v;
    __syncthreads();
    for (int off = 1; off < 1024; off <<= 1) {
        int t = (threadIdx.x >= off) ? sm[threadIdx.x - off] : 0;
        __syncthreads();
        sm[threadIdx.x] += t;
        __syncthreads();
    }
    if (threadIdx.x < nb) blocksum[threadIdx.x] = sm[threadIdx.x] - v;  // exclusive
}

__global__ void scan3_kernel(int* __restrict__ row_ptr, int N, const int* __restrict__ blocksum) {
    int i = blockIdx.x * 1024 + threadIdx.x;
    if (i < N) row_ptr[i + 1] += blocksum[blockIdx.x];
    if (i == 0) row_ptr[0] = 0;
}

// fused: CSR scatter + phase-1 coef (w=1 -> coef = nrm[src])
__global__ void scatter_kernel(const int* __restrict__ src, const int* __restrict__ dst, int E,
                               const int* __restrict__ row_ptr, int* __restrict__ cursor,
                               const float* __restrict__ nrm,
                               int* __restrict__ src_perm, float* __restrict__ coef) {
    int e = blockIdx.x * blockDim.x + threadIdx.x;
    if (e < E) {
        int d = dst[e];
        int s = src[e];
        int pos = row_ptr[d] + atomicAdd(&cursor[d], 1);
        src_perm[pos] = s;
        coef[pos] = nrm[s];
    }
}

__global__ void nrm_from_deg(const float* __restrict__ deg, int N,
                             float* __restrict__ nrm, float* __restrict__ invdt) {
    int i = blockIdx.x * blockDim.x + threadIdx.x;
    if (i < N) {
        float dt = deg[i];
        nrm[i] = 1.0f / sqrtf(dt);
        invdt[i] = 1.0f / dt;
    }
}

// coef[e] = w_perm[e] * nrm[src_perm[e]]  (phase 2)
__global__ void coef_kernel(const int* __restrict__ src_perm, const float* __restrict__ w_perm,
                            const float* __restrict__ nrm, int E, float* __restrict__ coef) {
    int e = blockIdx.x * blockDim.x + threadIdx.x;
    if (e < E) coef[e] = w_perm[e] * nrm[src_perm[e]];
}

// ---------------- main compute kernels ----------------

// one wave per node, lane = feature dim; gathers read bf16 shadow, 8 in flight
__global__ __launch_bounds__(256) void prop_kernel(
    const float* __restrict__ Yin, const ushort_t* __restrict__ Ybf,
    const float* __restrict__ X,
    const int* __restrict__ row_ptr, const int* __restrict__ src_perm,
    const float* __restrict__ coef, const float* __restrict__ nrm,
    const float* __restrict__ invdt, int N,
    float* __restrict__ Yout, ushort_t* __restrict__ Yout_bf) {
    int wave = (blockIdx.x * blockDim.x + threadIdx.x) >> 6;
    int lane = threadIdx.x & 63;
    if (wave >= N) return;
    int r0 = row_ptr[wave], r1 = row_ptr[wave + 1];
    float acc = 0.0f;
    for (int jb = r0; jb < r1; jb += 64) {
        int m = r1 - jb;
        if (m > 64) m = 64;
        int sv = 0;
        float cv = 0.0f;
        if (lane < m) { sv = src_perm[jb + lane]; cv = coef[jb + lane]; }
        for (int t = 0; t < m; t += 8) {
            float v[8], c[8];
            #pragma unroll
            for (int u = 0; u < 8; ++u) {
                int idx = t + u;
                int active = idx < m;
                if (!active) idx = 0;
                int s = __shfl(sv, idx, 64);
                float cc = __shfl(cv, idx, 64);
                c[u] = active ? cc : 0.0f;
                v[u] = bf2f(Ybf[(size_t)s * HID + lane]);    // 8 bf16 gathers in flight
            }
            #pragma unroll
            for (int u = 0; u < 8; ++u) acc += c[u] * v[u];
        }
    }
    size_t base = (size_t)wave * HID + lane;
    float out = 0.5f * Yin[base] + (0.5f * nrm[wave]) * acc + (0.5f * invdt[wave]) * X[base];
    Yout[base] = out;
    Yout_bf[base] = f2bf(out);
}

// attention: w_e = 1/max(sqrt(relu(||h_s-h_d||^2)+1e-7), tau) + 1e-9 ; deg = sum w per dst
// hd from fp32 (streaming), h_s gathered from bf16 shadow; 8 edges per batch
__global__ __launch_bounds__(256) void attn_kernel(
    const float* __restrict__ Y, const ushort_t* __restrict__ Ybf,
    const int* __restrict__ row_ptr, const int* __restrict__ src_perm, int N,
    float* __restrict__ w_perm, float* __restrict__ deg) {
    int wv = (blockIdx.x * blockDim.x + threadIdx.x) >> 6;
    int lane = threadIdx.x & 63;
    if (wv >= N) return;
    int r0 = row_ptr[wv], r1 = row_ptr[wv + 1];
    float hd = Y[(size_t)wv * HID + lane];
    float dacc = 0.0f;
    for (int jb = r0; jb < r1; jb += 64) {
        int m = r1 - jb;
        if (m > 64) m = 64;
        int sv = (lane < m) ? src_perm[jb + lane] : 0;
        float wreg = 0.0f;
        for (int t = 0; t < m; t += 8) {
            float ss[8];
            int act[8];
            #pragma unroll
            for (int u = 0; u < 8; ++u) {
                int idx = t + u;
                act[u] = idx < m;
                if (!act[u]) idx = 0;
                int s = __shfl(sv, idx, 64);
                float d = bf2f(Ybf[(size_t)s * HID + lane]) - hd;  // 8 gathers in flight
                ss[u] = d * d;
            }
            #pragma unroll
            for (int o = 32; o >= 1; o >>= 1) {
                #pragma unroll
                for (int u = 0; u < 8; ++u) ss[u] += __shfl_xor(ss[u], o, 64);
            }
            #pragma unroll
            for (int u = 0; u < 8; ++u) {
                float w = fmaxf(ss[u], 0.0f) + 1e-7f;  // relu + eps
                w = sqrtf(w);                           // pow(w, 1-0.5*p_rho), p_rho=1
                w = fmaxf(w, 0.2f);                     // tau clamp
                w = 1.0f / w + 1e-9f;
                if (act[u]) {
                    dacc += w;
                    if (lane == t + u) wreg = w;
                }
            }
        }
        if (lane < m) w_perm[jb + lane] = wreg;
    }
    if (lane == 0) deg[wv] = dacc;
}

// X = feat @ W_bef + b_bef  (128 -> 64). 8 rows/iter, thread = (rowpair, col). Writes fp32 + bf16.
__global__ __launch_bounds__(256) void gemm1_kernel(
    const float* __restrict__ feat, const float* __restrict__ W,
    const float* __restrict__ b, int N, float* __restrict__ X, ushort_t* __restrict__ Xbf) {
    __shared__ float Wl[IN_D * HID];     // 32 KB
    __shared__ float featL[8 * IN_D];    // 4 KB
    for (int i = threadIdx.x; i < IN_D * HID; i += 256) Wl[i] = W[i];
    int c = threadIdx.x & 63;
    int rsub = threadIdx.x >> 6;
    float bias = b[c];
    int ngroups = N / 8;                 // N = 100000 -> 12500 exactly
    const float4* feat4 = (const float4*)feat;
    for (int g = blockIdx.x; g < ngroups; g += gridDim.x) {
        __syncthreads();
        ((float4*)featL)[threadIdx.x] = feat4[(size_t)g * 256 + threadIdx.x];
        __syncthreads();
        const float4* f0 = (const float4*)&featL[rsub * IN_D];
        const float4* f1 = (const float4*)&featL[(rsub + 4) * IN_D];
        float acc0 = bias, acc1 = bias;
        #pragma unroll
        for (int k4 = 0; k4 < IN_D / 4; ++k4) {
            float4 a = f0[k4];
            float4 e = f1[k4];
            float w0 = Wl[(4 * k4 + 0) * HID + c];
            float w1 = Wl[(4 * k4 + 1) * HID + c];
            float w2 = Wl[(4 * k4 + 2) * HID + c];
            float w3 = Wl[(4 * k4 + 3) * HID + c];
            acc0 += a.x * w0 + a.y * w1 + a.z * w2 + a.w * w3;
            acc1 += e.x * w0 + e.y * w1 + e.z * w2 + e.w * w3;
        }
        size_t row = (size_t)g * 8;
        X[(row + rsub) * HID + c] = acc0;
        X[(row + rsub + 4) * HID + c] = acc1;
        Xbf[(row + rsub) * HID + c] = f2bf(acc0);
        Xbf[(row + rsub + 4) * HID + c] = f2bf(acc1);
    }
}

// out = relu(Y) @ W_aft + b_aft  (64 -> 64)
__global__ __launch_bounds__(256) void gemm2_kernel(
    const float* __restrict__ Y, const float* __restrict__ W,
    const float* __restrict__ b, int N, float* __restrict__ out) {
    __shared__ float Wl[HID * HID];      // 16 KB
    __shared__ float Yl[8 * HID];        // 2 KB
    for (int i = threadIdx.x; i < HID * HID; i += 256) Wl[i] = W[i];
    int c = threadIdx.x & 63;
    int rsub = threadIdx.x >> 6;
    float bias = b[c];
    int ngroups = N / 8;
    const float4* Y4 = (const float4*)Y;
    for (int g = blockIdx.x; g < ngroups; g += gridDim.x) {
        __syncthreads();
        if (threadIdx.x < 128) {
            float4 v = Y4[(size_t)g * 128 + threadIdx.x];
            v.x = fmaxf(v.x, 0.0f); v.y = fmaxf(v.y, 0.0f);
            v.z = fmaxf(v.z, 0.0f); v.w = fmaxf(v.w, 0.0f);
            ((float4*)Yl)[threadIdx.x] = v;
        }
        __syncthreads();
        const float4* f0 = (const float4*)&Yl[rsub * HID];
        const float4* f1 = (const float4*)&Yl[(rsub + 4) * HID];
        float acc0 = bias, acc1 = bias;
        #pragma unroll
        for (int k4 = 0; k4 < HID / 4; ++k4) {
            float4 a = f0[k4];
            float4 e = f1[k4];
            float w0 = Wl[(4 * k4 + 0) * HID + c];
            float w1 = Wl[(4 * k4 + 1) * HID + c];
            float w2 = Wl[(4 * k4 + 2) * HID + c];
            float w3 = Wl[(4 * k4 + 3) * HID + c];
            acc0 += a.x * w0 + a.y * w1 + a.z * w2 + a.w * w3;
            acc1 += e.x * w0 + e.y * w1 + e.z * w2 + e.w * w3;
        }
        size_t row = (size_t)g * 8;
        out[(row + rsub) * HID + c] = acc0;
        out[(row + rsub + 4) * HID + c] = acc1;
    }
}

// ---------------- launch ----------------

extern "C" void kernel_launch(void* const* d_in, const int* in_sizes, int n_in,
                              void* d_out, int out_size, void* d_ws, size_t ws_size,
                              hipStream_t stream) {
    const float* feat  = (const float*)d_in[0];
    const float* W_bef = (const float*)d_in[1];
    const float* b_bef = (const float*)d_in[2];
    const float* W_aft = (const float*)d_in[3];
    const float* b_aft = (const float*)d_in[4];
    const int*   src   = (const int*)d_in[5];
    const int*   dst   = (const int*)d_in[6];

    const int N = in_sizes[0] / IN_D;
    const int E = in_sizes[5];

    // workspace carve-up (256B-aligned)
    char* p = (char*)d_ws;
    auto alloc = [&](size_t bytes) -> void* {
        void* r = (void*)p;
        p += (bytes + 255) & ~(size_t)255;
        return r;
    };
    float*    X       = (float*)alloc((size_t)N * HID * 4);
    float*    Ya      = (float*)alloc((size_t)N * HID * 4);
    float*    Yb      = (float*)alloc((size_t)N * HID * 4);
    ushort_t* Xbf     = (ushort_t*)alloc((size_t)N * HID * 2);
    ushort_t* Yabf    = (ushort_t*)alloc((size_t)N * HID * 2);
    ushort_t* Ybbf    = (ushort_t*)alloc((size_t)N * HID * 2);
    int*      cnt     = (int*)alloc((size_t)N * 4);
    int*      cursor  = (int*)alloc((size_t)N * 4);
    int*      row_ptr = (int*)alloc((size_t)(N + 1) * 4);
    int*      blocksum= (int*)alloc(4096);
    int*      src_perm= (int*)alloc((size_t)E * 4);
    float*    w_perm  = (float*)alloc((size_t)E * 4);
    float*    coef    = (float*)alloc((size_t)E * 4);
    float*    deg     = (float*)alloc((size_t)N * 4);
    float*    nrm     = (float*)alloc((size_t)N * 4);
    float*    invdt   = (float*)alloc((size_t)N * 4);

    const int TB = 256;
    dim3 blk(TB);
    int gN   = (N + TB - 1) / TB;
    int gE   = (E + TB - 1) / TB;
    int gNW  = (N * 64 + TB - 1) / TB;     // wave-per-node kernels
    int nb   = (N + 1023) / 1024;          // scan blocks

    // --- CSR build ---
    zero2_kernel<<<gN, blk, 0, stream>>>(cnt, cursor, N);
    hist_kernel<<<gE, blk, 0, stream>>>(dst, E, cnt);
    scan1_kernel<<<nb, 1024, 0, stream>>>(cnt, N, row_ptr, blocksum, nrm, invdt);
    scan2_kernel<<<1, 1024, 0, stream>>>(blocksum, nb);
    scan3_kernel<<<nb, 1024, 0, stream>>>(row_ptr, N, blocksum);
    scatter_kernel<<<gE, blk, 0, stream>>>(src, dst, E, row_ptr, cursor, nrm, src_perm, coef);

    // --- MLP before ---
    gemm1_kernel<<<2048, blk, 0, stream>>>(feat, W_bef, b_bef, N, X, Xbf);

    // --- phase 1: w = 1 ---
    prop_kernel<<<gNW, blk, 0, stream>>>(X,  Xbf,  X, row_ptr, src_perm, coef, nrm, invdt, N, Ya, Yabf);
    prop_kernel<<<gNW, blk, 0, stream>>>(Ya, Yabf, X, row_ptr, src_perm, coef, nrm, invdt, N, Yb, Ybbf);
    prop_kernel<<<gNW, blk, 0, stream>>>(Yb, Ybbf, X, row_ptr, src_perm, coef, nrm, invdt, N, Ya, Yabf);
    prop_kernel<<<gNW, blk, 0, stream>>>(Ya, Yabf, X, row_ptr, src_perm, coef, nrm, invdt, N, Yb, Ybbf);

    // --- attention on Yb ---
    attn_kernel<<<gNW, blk, 0, stream>>>(Yb, Ybbf, row_ptr, src_perm, N, w_perm, deg);
    nrm_from_deg<<<gN, blk, 0, stream>>>(deg, N, nrm, invdt);
    coef_kernel<<<gE, blk, 0, stream>>>(src_perm, w_perm, nrm, E, coef);

    // --- phase 2: attention weights ---
    prop_kernel<<<gNW, blk, 0, stream>>>(Yb, Ybbf, X, row_ptr, src_perm, coef, nrm, invdt, N, Ya, Yabf);
    prop_kernel<<<gNW, blk, 0, stream>>>(Ya, Yabf, X, row_ptr, src_perm, coef, nrm, invdt, N, Yb, Ybbf);
    prop_kernel<<<gNW, blk, 0, stream>>>(Yb, Ybbf, X, row_ptr, src_perm, coef, nrm, invdt, N, Ya, Yabf);
    prop_kernel<<<gNW, blk, 0, stream>>>(Ya, Yabf, X, row_ptr, src_perm, coef, nrm, invdt, N, Yb, Ybbf);

    // --- MLP after ---
    gemm2_kernel<<<512, blk, 0, stream>>>(Yb, W_aft, b_aft, N, (float*)d_out);
}

// Round 4
// 641.082 us; speedup vs baseline: 1.1223x; 1.1223x over previous
//
#include <hip/hip_runtime.h>
#include <math.h>

#define IN_D 128
#define HID 64

typedef unsigned short ushort_t;
typedef unsigned int uint_t;

static __device__ __forceinline__ ushort_t f2bf(float f) {
    uint_t x = __float_as_uint(f);
    uint_t r = x + 0x7fffu + ((x >> 16) & 1u);   // RTN-even
    return (ushort_t)(r >> 16);
}
static __device__ __forceinline__ float bf2f(ushort_t u) {
    return __uint_as_float(((uint_t)u) << 16);
}

// ---------------- CSR build kernels ----------------

__global__ void zero1_kernel(int* a, int n) {
    int i = blockIdx.x * blockDim.x + threadIdx.x;
    if (i < n) a[i] = 0;
}

__global__ void hist_kernel(const int* __restrict__ dst, int E, int* __restrict__ cnt) {
    int e = blockIdx.x * blockDim.x + threadIdx.x;
    if (e < E) atomicAdd(&cnt[dst[e]], 1);
}

// inclusive scan within 1024-blocks; zeroes cnt after read (reused as scatter cursor);
// fused deg->nrm/invdt (phase 1: deg = int count, lam=1 -> dt = deg)
__global__ void scan1_kernel(int* __restrict__ cnt, int N,
                             int* __restrict__ row_ptr, int* __restrict__ blocksum,
                             float* __restrict__ nrm, float* __restrict__ invdt) {
    __shared__ int sm[1024];
    int i = blockIdx.x * 1024 + threadIdx.x;
    int v = (i < N) ? cnt[i] : 0;
    if (i < N) {
        cnt[i] = 0;                  // becomes cursor for scatter
        float d = (float)v;
        nrm[i] = 1.0f / sqrtf(d);
        invdt[i] = 1.0f / d;
    }
    sm[threadIdx.x] = v;
    __syncthreads();
    for (int off = 1; off < 1024; off <<= 1) {
        int t = (threadIdx.x >= off) ? sm[threadIdx.x - off] : 0;
        __syncthreads();
        sm[threadIdx.x] += t;
        __syncthreads();
    }
    if (i < N) row_ptr[i + 1] = sm[threadIdx.x];
    if (threadIdx.x == 1023) blocksum[blockIdx.x] = sm[1023];
}

__global__ void scan2_kernel(int* __restrict__ blocksum, int nb) {
    __shared__ int sm[1024];
    int v = (threadIdx.x < nb) ? blocksum[threadIdx.x] : 0;
    sm[threadIdx.x] = v;
    __syncthreads();
    for (int off = 1; off < 1024; off <<= 1) {
        int t = (threadIdx.x >= off) ? sm[threadIdx.x - off] : 0;
        __syncthreads();
        sm[threadIdx.x] += t;
        __syncthreads();
    }
    if (threadIdx.x < nb) blocksum[threadIdx.x] = sm[threadIdx.x] - v;  // exclusive
}

__global__ void scan3_kernel(int* __restrict__ row_ptr, int N, const int* __restrict__ blocksum) {
    int i = blockIdx.x * 1024 + threadIdx.x;
    if (i < N) row_ptr[i + 1] += blocksum[blockIdx.x];
    if (i == 0) row_ptr[0] = 0;
}

// CSR scatter + dst_perm + phase-1 coef (w=1 -> coef = nrm[src]); cursor = re-zeroed cnt
__global__ void scatter_kernel(const int* __restrict__ src, const int* __restrict__ dst, int E,
                               const int* __restrict__ row_ptr, int* __restrict__ cursor,
                               const float* __restrict__ nrm,
                               int* __restrict__ src_perm, int* __restrict__ dst_perm,
                               float* __restrict__ coef) {
    int e = blockIdx.x * blockDim.x + threadIdx.x;
    if (e < E) {
        int d = dst[e];
        int s = src[e];
        int pos = row_ptr[d] + atomicAdd(&cursor[d], 1);
        src_perm[pos] = s;
        dst_perm[pos] = d;
        coef[pos] = nrm[s];
    }
}

// coef[e] = w_perm[e] * nrm[src_perm[e]]  (phase 2)
__global__ void coef_kernel(const int* __restrict__ src_perm, const float* __restrict__ w_perm,
                            const float* __restrict__ nrm, int E, float* __restrict__ coef) {
    int e = blockIdx.x * blockDim.x + threadIdx.x;
    if (e < E) coef[e] = w_perm[e] * nrm[src_perm[e]];
}

// ---------------- main compute kernels ----------------

// one wave per node, lane = feature dim; bf16 gathers, 16 in flight before any FMA
__global__ __launch_bounds__(256) void prop_kernel(
    const float* __restrict__ Yin, const ushort_t* __restrict__ Ybf,
    const float* __restrict__ X,
    const int* __restrict__ row_ptr, const int* __restrict__ src_perm,
    const float* __restrict__ coef, const float* __restrict__ nrm,
    const float* __restrict__ invdt, int N,
    float* __restrict__ Yout, ushort_t* __restrict__ Yout_bf) {
    int wave = (blockIdx.x * blockDim.x + threadIdx.x) >> 6;
    int lane = threadIdx.x & 63;
    if (wave >= N) return;
    int r0 = row_ptr[wave], r1 = row_ptr[wave + 1];
    float acc = 0.0f;
    for (int jb = r0; jb < r1; jb += 64) {
        int m = r1 - jb;
        if (m > 64) m = 64;
        int sv = 0;
        float cv = 0.0f;
        if (lane < m) { sv = src_perm[jb + lane]; cv = coef[jb + lane]; }
        for (int t = 0; t < m; t += 16) {
            float v[16], c[16];
            #pragma unroll
            for (int u = 0; u < 16; ++u) {
                int idx = t + u;
                int active = idx < m;
                if (!active) idx = 0;
                int s = __shfl(sv, idx, 64);
                float cc = __shfl(cv, idx, 64);
                c[u] = active ? cc : 0.0f;
                v[u] = bf2f(Ybf[(size_t)s * HID + lane]);    // 16 bf16 gathers in flight
            }
            #pragma unroll
            for (int u = 0; u < 16; ++u) acc = fmaf(c[u], v[u], acc);
        }
    }
    size_t base = (size_t)wave * HID + lane;
    float out = 0.5f * Yin[base] + (0.5f * nrm[wave]) * acc + (0.5f * invdt[wave]) * X[base];
    Yout[base] = out;
    Yout_bf[base] = f2bf(out);
}

// edge-parallel attention: lane = edge; in-lane 64-dim distance, no cross-lane ops
// w_e = 1/max(sqrt(relu(||h_s-h_d||^2)+1e-7), tau) + 1e-9
__global__ __launch_bounds__(256) void attn_edge_kernel(
    const ushort_t* __restrict__ Ybf,
    const int* __restrict__ src_perm, const int* __restrict__ dst_perm,
    int E, float* __restrict__ w_perm) {
    int e = blockIdx.x * blockDim.x + threadIdx.x;
    if (e >= E) return;
    int s = src_perm[e], d = dst_perm[e];
    const uint4* ps = (const uint4*)(Ybf + (size_t)s * HID);
    const uint4* pd = (const uint4*)(Ybf + (size_t)d * HID);
    uint4 a[8], b[8];
    #pragma unroll
    for (int i = 0; i < 8; ++i) a[i] = ps[i];   // full src row: 8x16B in flight
    #pragma unroll
    for (int i = 0; i < 8; ++i) b[i] = pd[i];   // dst row (CSR-contiguous -> broadcast/L1)
    float ss = 0.0f;
    #pragma unroll
    for (int i = 0; i < 8; ++i) {
        const uint_t* ua = (const uint_t*)&a[i];
        const uint_t* ub = (const uint_t*)&b[i];
        #pragma unroll
        for (int j = 0; j < 4; ++j) {
            float slo = __uint_as_float(ua[j] << 16);
            float dlo = __uint_as_float(ub[j] << 16);
            float shi = __uint_as_float(ua[j] & 0xffff0000u);
            float dhi = __uint_as_float(ub[j] & 0xffff0000u);
            float t0 = slo - dlo;
            float t1 = shi - dhi;
            ss = fmaf(t0, t0, ss);
            ss = fmaf(t1, t1, ss);
        }
    }
    float w = fmaxf(ss, 0.0f) + 1e-7f;   // relu + eps
    w = sqrtf(w);                         // pow(w, 1-0.5*p_rho), p_rho=1
    w = fmaxf(w, 0.2f);                   // tau clamp
    w = 1.0f / w + 1e-9f;
    w_perm[e] = w;
}

// wave per node: deg[v] = sum of w_perm over CSR range; fused nrm/invdt (lam=1)
__global__ __launch_bounds__(256) void deg_sum_kernel(
    const float* __restrict__ w_perm, const int* __restrict__ row_ptr, int N,
    float* __restrict__ nrm, float* __restrict__ invdt) {
    int v = (blockIdx.x * blockDim.x + threadIdx.x) >> 6;
    int lane = threadIdx.x & 63;
    if (v >= N) return;
    int r0 = row_ptr[v], r1 = row_ptr[v + 1];
    float s = 0.0f;
    for (int j = r0 + lane; j < r1; j += 64) s += w_perm[j];
    #pragma unroll
    for (int o = 32; o >= 1; o >>= 1) s += __shfl_xor(s, o, 64);
    if (lane == 0) {
        nrm[v] = 1.0f / sqrtf(s);
        invdt[v] = 1.0f / s;
    }
}

// X = feat @ W_bef + b_bef  (128 -> 64). 8 rows/iter, thread = (rowpair, col). fp32 + bf16 out.
__global__ __launch_bounds__(256) void gemm1_kernel(
    const float* __restrict__ feat, const float* __restrict__ W,
    const float* __restrict__ b, int N, float* __restrict__ X, ushort_t* __restrict__ Xbf) {
    __shared__ float Wl[IN_D * HID];     // 32 KB
    __shared__ float featL[8 * IN_D];    // 4 KB
    for (int i = threadIdx.x; i < IN_D * HID; i += 256) Wl[i] = W[i];
    int c = threadIdx.x & 63;
    int rsub = threadIdx.x >> 6;
    float bias = b[c];
    int ngroups = N / 8;                 // N = 100000 -> 12500 exactly
    const float4* feat4 = (const float4*)feat;
    for (int g = blockIdx.x; g < ngroups; g += gridDim.x) {
        __syncthreads();
        ((float4*)featL)[threadIdx.x] = feat4[(size_t)g * 256 + threadIdx.x];
        __syncthreads();
        const float4* f0 = (const float4*)&featL[rsub * IN_D];
        const float4* f1 = (const float4*)&featL[(rsub + 4) * IN_D];
        float acc0 = bias, acc1 = bias;
        #pragma unroll
        for (int k4 = 0; k4 < IN_D / 4; ++k4) {
            float4 a = f0[k4];
            float4 e = f1[k4];
            float w0 = Wl[(4 * k4 + 0) * HID + c];
            float w1 = Wl[(4 * k4 + 1) * HID + c];
            float w2 = Wl[(4 * k4 + 2) * HID + c];
            float w3 = Wl[(4 * k4 + 3) * HID + c];
            acc0 += a.x * w0 + a.y * w1 + a.z * w2 + a.w * w3;
            acc1 += e.x * w0 + e.y * w1 + e.z * w2 + e.w * w3;
        }
        size_t row = (size_t)g * 8;
        X[(row + rsub) * HID + c] = acc0;
        X[(row + rsub + 4) * HID + c] = acc1;
        Xbf[(row + rsub) * HID + c] = f2bf(acc0);
        Xbf[(row + rsub + 4) * HID + c] = f2bf(acc1);
    }
}

// out = relu(Y) @ W_aft + b_aft  (64 -> 64)
__global__ __launch_bounds__(256) void gemm2_kernel(
    const float* __restrict__ Y, const float* __restrict__ W,
    const float* __restrict__ b, int N, float* __restrict__ out) {
    __shared__ float Wl[HID * HID];      // 16 KB
    __shared__ float Yl[8 * HID];        // 2 KB
    for (int i = threadIdx.x; i < HID * HID; i += 256) Wl[i] = W[i];
    int c = threadIdx.x & 63;
    int rsub = threadIdx.x >> 6;
    float bias = b[c];
    int ngroups = N / 8;
    const float4* Y4 = (const float4*)Y;
    for (int g = blockIdx.x; g < ngroups; g += gridDim.x) {
        __syncthreads();
        if (threadIdx.x < 128) {
            float4 v = Y4[(size_t)g * 128 + threadIdx.x];
            v.x = fmaxf(v.x, 0.0f); v.y = fmaxf(v.y, 0.0f);
            v.z = fmaxf(v.z, 0.0f); v.w = fmaxf(v.w, 0.0f);
            ((float4*)Yl)[threadIdx.x] = v;
        }
        __syncthreads();
        const float4* f0 = (const float4*)&Yl[rsub * HID];
        const float4* f1 = (const float4*)&Yl[(rsub + 4) * HID];
        float acc0 = bias, acc1 = bias;
        #pragma unroll
        for (int k4 = 0; k4 < HID / 4; ++k4) {
            float4 a = f0[k4];
            float4 e = f1[k4];
            float w0 = Wl[(4 * k4 + 0) * HID + c];
            float w1 = Wl[(4 * k4 + 1) * HID + c];
            float w2 = Wl[(4 * k4 + 2) * HID + c];
            float w3 = Wl[(4 * k4 + 3) * HID + c];
            acc0 += a.x * w0 + a.y * w1 + a.z * w2 + a.w * w3;
            acc1 += e.x * w0 + e.y * w1 + e.z * w2 + e.w * w3;
        }
        size_t row = (size_t)g * 8;
        out[(row + rsub) * HID + c] = acc0;
        out[(row + rsub + 4) * HID + c] = acc1;
    }
}

// ---------------- launch ----------------

extern "C" void kernel_launch(void* const* d_in, const int* in_sizes, int n_in,
                              void* d_out, int out_size, void* d_ws, size_t ws_size,
                              hipStream_t stream) {
    const float* feat  = (const float*)d_in[0];
    const float* W_bef = (const float*)d_in[1];
    const float* b_bef = (const float*)d_in[2];
    const float* W_aft = (const float*)d_in[3];
    const float* b_aft = (const float*)d_in[4];
    const int*   src   = (const int*)d_in[5];
    const int*   dst   = (const int*)d_in[6];

    const int N = in_sizes[0] / IN_D;
    const int E = in_sizes[5];

    // workspace carve-up (256B-aligned)
    char* p = (char*)d_ws;
    auto alloc = [&](size_t bytes) -> void* {
        void* r = (void*)p;
        p += (bytes + 255) & ~(size_t)255;
        return r;
    };
    float*    X       = (float*)alloc((size_t)N * HID * 4);
    float*    Ya      = (float*)alloc((size_t)N * HID * 4);
    float*    Yb      = (float*)alloc((size_t)N * HID * 4);
    ushort_t* Xbf     = (ushort_t*)alloc((size_t)N * HID * 2);
    ushort_t* Yabf    = (ushort_t*)alloc((size_t)N * HID * 2);
    ushort_t* Ybbf    = (ushort_t*)alloc((size_t)N * HID * 2);
    int*      cnt     = (int*)alloc((size_t)N * 4);       // doubles as scatter cursor
    int*      row_ptr = (int*)alloc((size_t)(N + 1) * 4);
    int*      blocksum= (int*)alloc(4096);
    int*      src_perm= (int*)alloc((size_t)E * 4);
    int*      dst_perm= (int*)alloc((size_t)E * 4);
    float*    w_perm  = (float*)alloc((size_t)E * 4);
    float*    coef    = (float*)alloc((size_t)E * 4);
    float*    nrm     = (float*)alloc((size_t)N * 4);
    float*    invdt   = (float*)alloc((size_t)N * 4);

    const int TB = 256;
    dim3 blk(TB);
    int gN   = (N + TB - 1) / TB;
    int gE   = (E + TB - 1) / TB;
    int gNW  = (N * 64 + TB - 1) / TB;     // wave-per-node kernels
    int nb   = (N + 1023) / 1024;          // scan blocks

    // --- CSR build ---
    zero1_kernel<<<gN, blk, 0, stream>>>(cnt, N);
    hist_kernel<<<gE, blk, 0, stream>>>(dst, E, cnt);
    scan1_kernel<<<nb, 1024, 0, stream>>>(cnt, N, row_ptr, blocksum, nrm, invdt);
    scan2_kernel<<<1, 1024, 0, stream>>>(blocksum, nb);
    scan3_kernel<<<nb, 1024, 0, stream>>>(row_ptr, N, blocksum);
    scatter_kernel<<<gE, blk, 0, stream>>>(src, dst, E, row_ptr, cnt, nrm,
                                           src_perm, dst_perm, coef);

    // --- MLP before ---
    gemm1_kernel<<<2048, blk, 0, stream>>>(feat, W_bef, b_bef, N, X, Xbf);

    // --- phase 1: w = 1 ---
    prop_kernel<<<gNW, blk, 0, stream>>>(X,  Xbf,  X, row_ptr, src_perm, coef, nrm, invdt, N, Ya, Yabf);
    prop_kernel<<<gNW, blk, 0, stream>>>(Ya, Yabf, X, row_ptr, src_perm, coef, nrm, invdt, N, Yb, Ybbf);
    prop_kernel<<<gNW, blk, 0, stream>>>(Yb, Ybbf, X, row_ptr, src_perm, coef, nrm, invdt, N, Ya, Yabf);
    prop_kernel<<<gNW, blk, 0, stream>>>(Ya, Yabf, X, row_ptr, src_perm, coef, nrm, invdt, N, Yb, Ybbf);

    // --- attention on Yb (edge-parallel) ---
    attn_edge_kernel<<<gE, blk, 0, stream>>>(Ybbf, src_perm, dst_perm, E, w_perm);
    deg_sum_kernel<<<gNW, blk, 0, stream>>>(w_perm, row_ptr, N, nrm, invdt);
    coef_kernel<<<gE, blk, 0, stream>>>(src_perm, w_perm, nrm, E, coef);

    // --- phase 2: attention weights ---
    prop_kernel<<<gNW, blk, 0, stream>>>(Yb, Ybbf, X, row_ptr, src_perm, coef, nrm, invdt, N, Ya, Yabf);
    prop_kernel<<<gNW, blk, 0, stream>>>(Ya, Yabf, X, row_ptr, src_perm, coef, nrm, invdt, N, Yb, Ybbf);
    prop_kernel<<<gNW, blk, 0, stream>>>(Yb, Ybbf, X, row_ptr, src_perm, coef, nrm, invdt, N, Ya, Yabf);
    prop_kernel<<<gNW, blk, 0, stream>>>(Ya, Yabf, X, row_ptr, src_perm, coef, nrm, invdt, N, Yb, Ybbf);

    // --- MLP after ---
    gemm2_kernel<<<512, blk, 0, stream>>>(Yb, W_aft, b_aft, N, (float*)d_out);
}

// Round 5
// 615.294 us; speedup vs baseline: 1.1694x; 1.0419x over previous
//
#include <hip/hip_runtime.h>
#include <math.h>

#define IN_D 128
#define HID 64

typedef unsigned short ushort_t;
typedef unsigned int uint_t;

static __device__ __forceinline__ ushort_t f2bf(float f) {
    uint_t x = __float_as_uint(f);
    uint_t r = x + 0x7fffu + ((x >> 16) & 1u);   // RTN-even
    return (ushort_t)(r >> 16);
}
static __device__ __forceinline__ float bf2f(ushort_t u) {
    return __uint_as_float(((uint_t)u) << 16);
}

// ---------------- CSR build kernels ----------------

__global__ void zero1_kernel(int* a, int n) {
    int i = blockIdx.x * blockDim.x + threadIdx.x;
    if (i < n) a[i] = 0;
}

__global__ void hist_kernel(const int* __restrict__ dst, int E, int* __restrict__ cnt) {
    int e = blockIdx.x * blockDim.x + threadIdx.x;
    if (e < E) atomicAdd(&cnt[dst[e]], 1);
}

// inclusive scan within 1024-blocks; zeroes cnt after read (reused as scatter cursor);
// fused deg->nrm/invdt (phase 1: deg = int count, lam=1 -> dt = deg)
__global__ void scan1_kernel(int* __restrict__ cnt, int N,
                             int* __restrict__ row_ptr, int* __restrict__ blocksum,
                             float* __restrict__ nrm, float* __restrict__ invdt) {
    __shared__ int sm[1024];
    int i = blockIdx.x * 1024 + threadIdx.x;
    int v = (i < N) ? cnt[i] : 0;
    if (i < N) {
        cnt[i] = 0;                  // becomes cursor for scatter
        float d = (float)v;
        nrm[i] = 1.0f / sqrtf(d);
        invdt[i] = 1.0f / d;
    }
    sm[threadIdx.x] = v;
    __syncthreads();
    for (int off = 1; off < 1024; off <<= 1) {
        int t = (threadIdx.x >= off) ? sm[threadIdx.x - off] : 0;
        __syncthreads();
        sm[threadIdx.x] += t;
        __syncthreads();
    }
    if (i < N) row_ptr[i + 1] = sm[threadIdx.x];
    if (threadIdx.x == 1023) blocksum[blockIdx.x] = sm[1023];
}

__global__ void scan2_kernel(int* __restrict__ blocksum, int nb) {
    __shared__ int sm[1024];
    int v = (threadIdx.x < nb) ? blocksum[threadIdx.x] : 0;
    sm[threadIdx.x] = v;
    __syncthreads();
    for (int off = 1; off < 1024; off <<= 1) {
        int t = (threadIdx.x >= off) ? sm[threadIdx.x - off] : 0;
        __syncthreads();
        sm[threadIdx.x] += t;
        __syncthreads();
    }
    if (threadIdx.x < nb) blocksum[threadIdx.x] = sm[threadIdx.x] - v;  // exclusive
}

__global__ void scan3_kernel(int* __restrict__ row_ptr, int N, const int* __restrict__ blocksum) {
    int i = blockIdx.x * 1024 + threadIdx.x;
    if (i < N) row_ptr[i + 1] += blocksum[blockIdx.x];
    if (i == 0) row_ptr[0] = 0;
}

// CSR scatter + dst_perm + phase-1 coef (w=1 -> coef = nrm[src]); cursor = re-zeroed cnt
__global__ void scatter_kernel(const int* __restrict__ src, const int* __restrict__ dst, int E,
                               const int* __restrict__ row_ptr, int* __restrict__ cursor,
                               const float* __restrict__ nrm,
                               int* __restrict__ src_perm, int* __restrict__ dst_perm,
                               float* __restrict__ coef) {
    int e = blockIdx.x * blockDim.x + threadIdx.x;
    if (e < E) {
        int d = dst[e];
        int s = src[e];
        int pos = row_ptr[d] + atomicAdd(&cursor[d], 1);
        src_perm[pos] = s;
        dst_perm[pos] = d;
        coef[pos] = nrm[s];
    }
}

// coef[e] = w_perm[e] * nrm[src_perm[e]]  (phase 2)
__global__ void coef_kernel(const int* __restrict__ src_perm, const float* __restrict__ w_perm,
                            const float* __restrict__ nrm, int E, float* __restrict__ coef) {
    int e = blockIdx.x * blockDim.x + threadIdx.x;
    if (e < E) coef[e] = w_perm[e] * nrm[src_perm[e]];
}

// ---------------- main compute kernels ----------------

// one wave per node, lane = feature dim. Wave index forced uniform (SGPR) so the
// CSR walk (row_ptr, src_perm, coef) compiles to scalar loads; the gather is a
// global_load_ushort with SGPR base + invariant lane offset. ~3 wave-slots/edge.
__global__ __launch_bounds__(256) void prop_kernel(
    const float* __restrict__ Yin, const ushort_t* __restrict__ Ybf,
    const float* __restrict__ X,
    const int* __restrict__ row_ptr, const int* __restrict__ src_perm,
    const float* __restrict__ coef, const float* __restrict__ nrm,
    const float* __restrict__ invdt, int N,
    float* __restrict__ Yout, ushort_t* __restrict__ Yout_bf) {
    int wave = __builtin_amdgcn_readfirstlane((blockIdx.x * blockDim.x + threadIdx.x) >> 6);
    int lane = threadIdx.x & 63;
    if (wave >= N) return;
    int r0 = row_ptr[wave], r1 = row_ptr[wave + 1];
    float acc = 0.0f;
    int j = r0;
    for (; j + 4 <= r1; j += 4) {                 // full batches, uniform control
        float v[4], c[4];
        #pragma unroll
        for (int u = 0; u < 4; ++u) {
            int s = src_perm[j + u];              // scalar load
            c[u] = coef[j + u];                   // scalar load
            v[u] = bf2f(Ybf[(size_t)s * HID + lane]);  // saddr gather
        }
        #pragma unroll
        for (int u = 0; u < 4; ++u) acc = fmaf(c[u], v[u], acc);
    }
    if (j < r1) {                                 // clamped tail, coef zeroed
        float v[4], c[4];
        #pragma unroll
        for (int u = 0; u < 4; ++u) {
            int jj = j + u;
            int valid = jj < r1;
            int idx = valid ? jj : r1 - 1;
            int s = src_perm[idx];
            float cc = coef[idx];
            c[u] = valid ? cc : 0.0f;
            v[u] = bf2f(Ybf[(size_t)s * HID + lane]);
        }
        #pragma unroll
        for (int u = 0; u < 4; ++u) acc = fmaf(c[u], v[u], acc);
    }
    size_t base = (size_t)wave * HID + lane;
    float out = 0.5f * Yin[base] + (0.5f * nrm[wave]) * acc + (0.5f * invdt[wave]) * X[base];
    Yout[base] = out;
    Yout_bf[base] = f2bf(out);
}

// edge-parallel attention: lane = edge; in-lane 64-dim distance, no cross-lane ops
// w_e = 1/max(sqrt(relu(||h_s-h_d||^2)+1e-7), tau) + 1e-9
__global__ __launch_bounds__(256) void attn_edge_kernel(
    const ushort_t* __restrict__ Ybf,
    const int* __restrict__ src_perm, const int* __restrict__ dst_perm,
    int E, float* __restrict__ w_perm) {
    int e = blockIdx.x * blockDim.x + threadIdx.x;
    if (e >= E) return;
    int s = src_perm[e], d = dst_perm[e];
    const uint4* ps = (const uint4*)(Ybf + (size_t)s * HID);
    const uint4* pd = (const uint4*)(Ybf + (size_t)d * HID);
    uint4 a[8], b[8];
    #pragma unroll
    for (int i = 0; i < 8; ++i) a[i] = ps[i];   // full src row: 8x16B in flight
    #pragma unroll
    for (int i = 0; i < 8; ++i) b[i] = pd[i];   // dst row (CSR-contiguous -> L1 hits)
    float ss = 0.0f;
    #pragma unroll
    for (int i = 0; i < 8; ++i) {
        const uint_t* ua = (const uint_t*)&a[i];
        const uint_t* ub = (const uint_t*)&b[i];
        #pragma unroll
        for (int j = 0; j < 4; ++j) {
            float slo = __uint_as_float(ua[j] << 16);
            float dlo = __uint_as_float(ub[j] << 16);
            float shi = __uint_as_float(ua[j] & 0xffff0000u);
            float dhi = __uint_as_float(ub[j] & 0xffff0000u);
            float t0 = slo - dlo;
            float t1 = shi - dhi;
            ss = fmaf(t0, t0, ss);
            ss = fmaf(t1, t1, ss);
        }
    }
    float w = fmaxf(ss, 0.0f) + 1e-7f;   // relu + eps
    w = sqrtf(w);                         // pow(w, 1-0.5*p_rho), p_rho=1
    w = fmaxf(w, 0.2f);                   // tau clamp
    w = 1.0f / w + 1e-9f;
    w_perm[e] = w;
}

// wave per node: deg[v] = sum of w_perm over CSR range; fused nrm/invdt (lam=1)
__global__ __launch_bounds__(256) void deg_sum_kernel(
    const float* __restrict__ w_perm, const int* __restrict__ row_ptr, int N,
    float* __restrict__ nrm, float* __restrict__ invdt) {
    int v = (blockIdx.x * blockDim.x + threadIdx.x) >> 6;
    int lane = threadIdx.x & 63;
    if (v >= N) return;
    int r0 = row_ptr[v], r1 = row_ptr[v + 1];
    float s = 0.0f;
    for (int j = r0 + lane; j < r1; j += 64) s += w_perm[j];
    #pragma unroll
    for (int o = 32; o >= 1; o >>= 1) s += __shfl_xor(s, o, 64);
    if (lane == 0) {
        nrm[v] = 1.0f / sqrtf(s);
        invdt[v] = 1.0f / s;
    }
}

// X = feat @ W_bef + b_bef  (128 -> 64). 16 rows/iter, 4 rows/thread. fp32 + bf16 out.
__global__ __launch_bounds__(256) void gemm1_kernel(
    const float* __restrict__ feat, const float* __restrict__ W,
    const float* __restrict__ b, int N, float* __restrict__ X, ushort_t* __restrict__ Xbf) {
    __shared__ float Wl[IN_D * HID];     // 32 KB
    __shared__ float featL[16 * IN_D];   // 8 KB
    for (int i = threadIdx.x; i < IN_D * HID; i += 256) Wl[i] = W[i];
    int c = threadIdx.x & 63;
    int rsub = threadIdx.x >> 6;         // 0..3
    float bias = b[c];
    int ngroups = N / 16;                // N = 100000 -> 6250 exactly
    const float4* feat4 = (const float4*)feat;
    for (int g = blockIdx.x; g < ngroups; g += gridDim.x) {
        __syncthreads();
        float4* fl4 = (float4*)featL;
        fl4[threadIdx.x]       = feat4[(size_t)g * 512 + threadIdx.x];
        fl4[threadIdx.x + 256] = feat4[(size_t)g * 512 + 256 + threadIdx.x];
        __syncthreads();
        const float4* f0 = (const float4*)&featL[(rsub) * IN_D];
        const float4* f1 = (const float4*)&featL[(rsub + 4) * IN_D];
        const float4* f2 = (const float4*)&featL[(rsub + 8) * IN_D];
        const float4* f3 = (const float4*)&featL[(rsub + 12) * IN_D];
        float acc0 = bias, acc1 = bias, acc2 = bias, acc3 = bias;
        #pragma unroll
        for (int k4 = 0; k4 < IN_D / 4; ++k4) {
            float4 a = f0[k4];
            float4 e = f1[k4];
            float4 h = f2[k4];
            float4 q = f3[k4];
            float w0 = Wl[(4 * k4 + 0) * HID + c];
            float w1 = Wl[(4 * k4 + 1) * HID + c];
            float w2 = Wl[(4 * k4 + 2) * HID + c];
            float w3 = Wl[(4 * k4 + 3) * HID + c];
            acc0 += a.x * w0 + a.y * w1 + a.z * w2 + a.w * w3;
            acc1 += e.x * w0 + e.y * w1 + e.z * w2 + e.w * w3;
            acc2 += h.x * w0 + h.y * w1 + h.z * w2 + h.w * w3;
            acc3 += q.x * w0 + q.y * w1 + q.z * w2 + q.w * w3;
        }
        size_t row = (size_t)g * 16;
        X[(row + rsub) * HID + c] = acc0;
        X[(row + rsub + 4) * HID + c] = acc1;
        X[(row + rsub + 8) * HID + c] = acc2;
        X[(row + rsub + 12) * HID + c] = acc3;
        Xbf[(row + rsub) * HID + c] = f2bf(acc0);
        Xbf[(row + rsub + 4) * HID + c] = f2bf(acc1);
        Xbf[(row + rsub + 8) * HID + c] = f2bf(acc2);
        Xbf[(row + rsub + 12) * HID + c] = f2bf(acc3);
    }
}

// out = relu(Y) @ W_aft + b_aft  (64 -> 64). 16 rows/iter, 4 rows/thread.
__global__ __launch_bounds__(256) void gemm2_kernel(
    const float* __restrict__ Y, const float* __restrict__ W,
    const float* __restrict__ b, int N, float* __restrict__ out) {
    __shared__ float Wl[HID * HID];      // 16 KB
    __shared__ float Yl[16 * HID];       // 4 KB
    for (int i = threadIdx.x; i < HID * HID; i += 256) Wl[i] = W[i];
    int c = threadIdx.x & 63;
    int rsub = threadIdx.x >> 6;
    float bias = b[c];
    int ngroups = N / 16;
    const float4* Y4 = (const float4*)Y;
    for (int g = blockIdx.x; g < ngroups; g += gridDim.x) {
        __syncthreads();
        {
            float4 v = Y4[(size_t)g * 256 + threadIdx.x];
            v.x = fmaxf(v.x, 0.0f); v.y = fmaxf(v.y, 0.0f);
            v.z = fmaxf(v.z, 0.0f); v.w = fmaxf(v.w, 0.0f);
            ((float4*)Yl)[threadIdx.x] = v;
        }
        __syncthreads();
        const float4* f0 = (const float4*)&Yl[(rsub) * HID];
        const float4* f1 = (const float4*)&Yl[(rsub + 4) * HID];
        const float4* f2 = (const float4*)&Yl[(rsub + 8) * HID];
        const float4* f3 = (const float4*)&Yl[(rsub + 12) * HID];
        float acc0 = bias, acc1 = bias, acc2 = bias, acc3 = bias;
        #pragma unroll
        for (int k4 = 0; k4 < HID / 4; ++k4) {
            float4 a = f0[k4];
            float4 e = f1[k4];
            float4 h = f2[k4];
            float4 q = f3[k4];
            float w0 = Wl[(4 * k4 + 0) * HID + c];
            float w1 = Wl[(4 * k4 + 1) * HID + c];
            float w2 = Wl[(4 * k4 + 2) * HID + c];
            float w3 = Wl[(4 * k4 + 3) * HID + c];
            acc0 += a.x * w0 + a.y * w1 + a.z * w2 + a.w * w3;
            acc1 += e.x * w0 + e.y * w1 + e.z * w2 + e.w * w3;
            acc2 += h.x * w0 + h.y * w1 + h.z * w2 + h.w * w3;
            acc3 += q.x * w0 + q.y * w1 + q.z * w2 + q.w * w3;
        }
        size_t row = (size_t)g * 16;
        out[(row + rsub) * HID + c] = acc0;
        out[(row + rsub + 4) * HID + c] = acc1;
        out[(row + rsub + 8) * HID + c] = acc2;
        out[(row + rsub + 12) * HID + c] = acc3;
    }
}

// ---------------- launch ----------------

extern "C" void kernel_launch(void* const* d_in, const int* in_sizes, int n_in,
                              void* d_out, int out_size, void* d_ws, size_t ws_size,
                              hipStream_t stream) {
    const float* feat  = (const float*)d_in[0];
    const float* W_bef = (const float*)d_in[1];
    const float* b_bef = (const float*)d_in[2];
    const float* W_aft = (const float*)d_in[3];
    const float* b_aft = (const float*)d_in[4];
    const int*   src   = (const int*)d_in[5];
    const int*   dst   = (const int*)d_in[6];

    const int N = in_sizes[0] / IN_D;
    const int E = in_sizes[5];

    // workspace carve-up (256B-aligned)
    char* p = (char*)d_ws;
    auto alloc = [&](size_t bytes) -> void* {
        void* r = (void*)p;
        p += (bytes + 255) & ~(size_t)255;
        return r;
    };
    float*    X       = (float*)alloc((size_t)N * HID * 4);
    float*    Ya      = (float*)alloc((size_t)N * HID * 4);
    float*    Yb      = (float*)alloc((size_t)N * HID * 4);
    ushort_t* Xbf     = (ushort_t*)alloc((size_t)N * HID * 2);
    ushort_t* Yabf    = (ushort_t*)alloc((size_t)N * HID * 2);
    ushort_t* Ybbf    = (ushort_t*)alloc((size_t)N * HID * 2);
    int*      cnt     = (int*)alloc((size_t)N * 4);       // doubles as scatter cursor
    int*      row_ptr = (int*)alloc((size_t)(N + 1) * 4);
    int*      blocksum= (int*)alloc(4096);
    int*      src_perm= (int*)alloc((size_t)E * 4);
    int*      dst_perm= (int*)alloc((size_t)E * 4);
    float*    w_perm  = (float*)alloc((size_t)E * 4);
    float*    coef    = (float*)alloc((size_t)E * 4);
    float*    nrm     = (float*)alloc((size_t)N * 4);
    float*    invdt   = (float*)alloc((size_t)N * 4);

    const int TB = 256;
    dim3 blk(TB);
    int gN   = (N + TB - 1) / TB;
    int gE   = (E + TB - 1) / TB;
    int gNW  = (N * 64 + TB - 1) / TB;     // wave-per-node kernels
    int nb   = (N + 1023) / 1024;          // scan blocks

    // --- CSR build ---
    zero1_kernel<<<gN, blk, 0, stream>>>(cnt, N);
    hist_kernel<<<gE, blk, 0, stream>>>(dst, E, cnt);
    scan1_kernel<<<nb, 1024, 0, stream>>>(cnt, N, row_ptr, blocksum, nrm, invdt);
    scan2_kernel<<<1, 1024, 0, stream>>>(blocksum, nb);
    scan3_kernel<<<nb, 1024, 0, stream>>>(row_ptr, N, blocksum);
    scatter_kernel<<<gE, blk, 0, stream>>>(src, dst, E, row_ptr, cnt, nrm,
                                           src_perm, dst_perm, coef);

    // --- MLP before ---
    gemm1_kernel<<<2048, blk, 0, stream>>>(feat, W_bef, b_bef, N, X, Xbf);

    // --- phase 1: w = 1 ---
    prop_kernel<<<gNW, blk, 0, stream>>>(X,  Xbf,  X, row_ptr, src_perm, coef, nrm, invdt, N, Ya, Yabf);
    prop_kernel<<<gNW, blk, 0, stream>>>(Ya, Yabf, X, row_ptr, src_perm, coef, nrm, invdt, N, Yb, Ybbf);
    prop_kernel<<<gNW, blk, 0, stream>>>(Yb, Ybbf, X, row_ptr, src_perm, coef, nrm, invdt, N, Ya, Yabf);
    prop_kernel<<<gNW, blk, 0, stream>>>(Ya, Yabf, X, row_ptr, src_perm, coef, nrm, invdt, N, Yb, Ybbf);

    // --- attention on Yb (edge-parallel) ---
    attn_edge_kernel<<<gE, blk, 0, stream>>>(Ybbf, src_perm, dst_perm, E, w_perm);
    deg_sum_kernel<<<gNW, blk, 0, stream>>>(w_perm, row_ptr, N, nrm, invdt);
    coef_kernel<<<gE, blk, 0, stream>>>(src_perm, w_perm, nrm, E, coef);

    // --- phase 2: attention weights ---
    prop_kernel<<<gNW, blk, 0, stream>>>(Yb, Ybbf, X, row_ptr, src_perm, coef, nrm, invdt, N, Ya, Yabf);
    prop_kernel<<<gNW, blk, 0, stream>>>(Ya, Yabf, X, row_ptr, src_perm, coef, nrm, invdt, N, Yb, Ybbf);
    prop_kernel<<<gNW, blk, 0, stream>>>(Yb, Ybbf, X, row_ptr, src_perm, coef, nrm, invdt, N, Ya, Yabf);
    prop_kernel<<<gNW, blk, 0, stream>>>(Ya, Yabf, X, row_ptr, src_perm, coef, nrm, invdt, N, Yb, Ybbf);

    // --- MLP after ---
    gemm2_kernel<<<512, blk, 0, stream>>>(Yb, W_aft, b_aft, N, (float*)d_out);
}